// Round 1
// baseline (1059.371 us; speedup 1.0000x reference)
//
#include <hip/hip_runtime.h>

#define UU 3000
#define SS 1500
#define TT 32
#define BB 16384
#define KK 50

// ---------------------------------------------------------------------------
// Kernel 1: classify the mask buffer's element encoding.
//   flag = 0 : int32  (words are 0/1)
//   flag = 2 : float32 (words are 0.0f / 1.0f)
//   flag = 1 : uint8  (bytes 0/1 -> words look like 0x00010101 etc.)
// Deterministic for fixed inputs; same work every call (graph-safe).
// ---------------------------------------------------------------------------
__global__ __launch_bounds__(256) void detect_mask(const unsigned int* __restrict__ mask,
                                                   int* __restrict__ flag) {
    __shared__ int bad_i32, bad_f32;
    if (threadIdx.x == 0) { bad_i32 = 0; bad_f32 = 0; }
    __syncthreads();
    for (int i = threadIdx.x; i < 4096; i += 256) {
        unsigned int w = mask[i];
        if (w > 1u) bad_i32 = 1;
        if (w != 0u && w != 0x3F800000u) bad_f32 = 1;
    }
    __syncthreads();
    if (threadIdx.x == 0) {
        int f = 0;
        if (bad_i32) f = bad_f32 ? 1 : 2;
        *flag = f;
    }
}

// ---------------------------------------------------------------------------
// Kernel 2: per-user top-50 of user_sim rows.
// One block per user. Row staged in LDS as uint64 keys:
//   high 32 = order-preserving float bits, low 32 = (0xFFFFFFFF - index)
// so max-key == (max value, then min index) -- matches jax.lax.top_k
// tie-breaking at the rank-50 membership boundary.
// 50 rounds of block-wide argmax; selected key zeroed (all real keys > 0,
// since even -1.0 encodes to high word 0x407FFFFF).
// ---------------------------------------------------------------------------
__global__ __launch_bounds__(256) void topk_kernel(const float* __restrict__ user_sim,
                                                   int* __restrict__ topk_idx,
                                                   float* __restrict__ topk_val) {
    __shared__ unsigned long long keys[UU];   // 24000 B
    __shared__ unsigned long long wmax[4];
    const int u = blockIdx.x;
    const float* row = user_sim + (size_t)u * UU;

    for (int i = threadIdx.x; i < UU; i += 256) {
        unsigned int b = __float_as_uint(row[i]);
        b = (b & 0x80000000u) ? ~b : (b | 0x80000000u);  // monotonic map
        keys[i] = ((unsigned long long)b << 32) | (unsigned int)(0xFFFFFFFFu - (unsigned int)i);
    }
    __syncthreads();

    for (int k = 0; k < KK; ++k) {
        unsigned long long best = 0ull;
        for (int i = threadIdx.x; i < UU; i += 256) {
            unsigned long long v = keys[i];
            best = (v > best) ? v : best;
        }
        // 64-lane butterfly max
        for (int m = 32; m >= 1; m >>= 1) {
            unsigned long long o = __shfl_xor(best, m, 64);
            best = (o > best) ? o : best;
        }
        if ((threadIdx.x & 63) == 0) wmax[threadIdx.x >> 6] = best;
        __syncthreads();
        if (threadIdx.x == 0) {
            best = wmax[0];
            for (int w = 1; w < 4; ++w) best = (wmax[w] > best) ? wmax[w] : best;
            unsigned int idx = 0xFFFFFFFFu - (unsigned int)(best & 0xFFFFFFFFull);
            unsigned int ub  = (unsigned int)(best >> 32);
            float f = (ub & 0x80000000u) ? __uint_as_float(ub & 0x7FFFFFFFu)
                                         : __uint_as_float(~ub);
            topk_idx[u * KK + k] = (int)idx;
            topk_val[u * KK + k] = f;
            keys[idx] = 0ull;                 // remove from candidates
        }
        __syncthreads();
    }
}

// ---------------------------------------------------------------------------
// Kernel 3: one 64-lane wave per batch element. Lanes 0..49 gather one
// neighbor each (mask, qos, avg), butterfly-reduce sim_sum / dev_sum.
// ---------------------------------------------------------------------------
__global__ __launch_bounds__(256) void gather_kernel(
    const float* __restrict__ qos, const void* __restrict__ mask,
    const float* __restrict__ avg, const int* __restrict__ time_ids,
    const int* __restrict__ user_ids, const int* __restrict__ service_ids,
    const int* __restrict__ topk_idx, const float* __restrict__ topk_val,
    const int* __restrict__ flag, float* __restrict__ out) {

    const int wave = (int)((blockIdx.x * blockDim.x + threadIdx.x) >> 6);
    const int lane = (int)(threadIdx.x & 63);
    if (wave >= BB) return;

    const int u = user_ids[wave];
    const int s = service_ids[wave];
    const int t = time_ids[wave];
    const float base = avg[(size_t)u * SS + s];
    const int fl = *flag;   // wave-uniform, L2-hot

    float wv = 0.0f, dv = 0.0f;
    if (lane < KK) {
        const int   idx = topk_idx[u * KK + lane];
        const float val = topk_val[u * KK + lane];
        const size_t off3 = ((size_t)idx * SS + s) * TT + t;
        int m;
        if (fl == 0)       m = ((const int*)mask)[off3];
        else if (fl == 1)  m = (int)((const unsigned char*)mask)[off3];
        else               m = (((const float*)mask)[off3] != 0.0f) ? 1 : 0;
        if (m) {
            const float q = qos[off3];
            const float a = avg[(size_t)idx * SS + s];
            wv = val;
            dv = val * (q - a);
        }
    }
    for (int m2 = 32; m2 >= 1; m2 >>= 1) {
        wv += __shfl_xor(wv, m2, 64);
        dv += __shfl_xor(dv, m2, 64);
    }
    if (lane == 0) {
        const float deviation = (wv > 0.0f) ? (dv / wv) : 0.0f;
        const float r = base + deviation;
        out[wave] = (r > 0.0f) ? r : 0.0f;
    }
}

extern "C" void kernel_launch(void* const* d_in, const int* in_sizes, int n_in,
                              void* d_out, int out_size, void* d_ws, size_t ws_size,
                              hipStream_t stream) {
    const float* qos      = (const float*)d_in[0];
    const void*  mask     = d_in[1];
    const float* avg      = (const float*)d_in[2];
    const float* user_sim = (const float*)d_in[3];
    const int* time_ids    = (const int*)d_in[4];
    const int* user_ids    = (const int*)d_in[5];
    const int* service_ids = (const int*)d_in[6];
    float* out = (float*)d_out;

    // workspace layout: [topk_idx: U*K int][topk_val: U*K float][flag: int]
    int*   topk_idx = (int*)d_ws;
    float* topk_val = (float*)((char*)d_ws + (size_t)UU * KK * 4);
    int*   flag     = (int*)((char*)d_ws + (size_t)UU * KK * 8);

    detect_mask<<<1, 256, 0, stream>>>((const unsigned int*)mask, flag);
    topk_kernel<<<UU, 256, 0, stream>>>(user_sim, topk_idx, topk_val);
    gather_kernel<<<(BB * 64) / 256, 256, 0, stream>>>(
        qos, mask, avg, time_ids, user_ids, service_ids,
        topk_idx, topk_val, flag, out);
}

// Round 2
// 947.914 us; speedup vs baseline: 1.1176x; 1.1176x over previous
//
#include <hip/hip_runtime.h>

#define UU 3000
#define SS 1500
#define TT 32
#define BB 16384
#define KK 50

// ---------------------------------------------------------------------------
// Kernel 1: classify the mask buffer's element encoding.
//   flag = 0 : int32 (words 0/1), 1 : uint8 (packed bytes), 2 : float32
// ---------------------------------------------------------------------------
__global__ __launch_bounds__(256) void detect_mask(const unsigned int* __restrict__ mask,
                                                   int* __restrict__ flag) {
    __shared__ int bad_i32, bad_f32;
    if (threadIdx.x == 0) { bad_i32 = 0; bad_f32 = 0; }
    __syncthreads();
    for (int i = threadIdx.x; i < 4096; i += 256) {
        unsigned int w = mask[i];
        if (w > 1u) bad_i32 = 1;
        if (w != 0u && w != 0x3F800000u) bad_f32 = 1;
    }
    __syncthreads();
    if (threadIdx.x == 0) {
        int f = 0;
        if (bad_i32) f = bad_f32 ? 1 : 2;
        *flag = f;
    }
}

// order-preserving float<->uint map
__device__ __forceinline__ unsigned int float_to_key(float f) {
    unsigned int b = __float_as_uint(f);
    return (b & 0x80000000u) ? ~b : (b | 0x80000000u);
}
__device__ __forceinline__ float key_to_float(unsigned int k) {
    return (k & 0x80000000u) ? __uint_as_float(k & 0x7FFFFFFFu)
                             : __uint_as_float(~k);
}

// ---------------------------------------------------------------------------
// Kernel 2: per-user top-50 via 4-pass 8-bit radix select.
// One block per user. Finds thr = exact 50th-largest key; emits all keys
// > thr (arbitrary order — downstream sum is order-independent) plus the
// `remaining` smallest-index keys == thr (jax tie-break).
// ---------------------------------------------------------------------------
__global__ __launch_bounds__(256) void topk_select(const float* __restrict__ user_sim,
                                                   int* __restrict__ topk_idx,
                                                   float* __restrict__ topk_val) {
    __shared__ unsigned int keys[UU];   // 12000 B
    __shared__ int hist[256];
    __shared__ int s_bin, s_rem;
    __shared__ int cnt_gt, eq_cnt;
    __shared__ int eq_list[64];

    const int u = blockIdx.x;
    const float* row = user_sim + (size_t)u * UU;

    for (int i = threadIdx.x; i < UU; i += 256)
        keys[i] = float_to_key(row[i]);
    if (threadIdx.x == 0) { cnt_gt = 0; eq_cnt = 0; }

    unsigned int prefix = 0u, prefmask = 0u;
    int remaining = KK;

    for (int pass = 0; pass < 4; ++pass) {
        const int shift = 24 - pass * 8;
        hist[threadIdx.x] = 0;
        __syncthreads();
        for (int i = threadIdx.x; i < UU; i += 256) {
            unsigned int k = keys[i];
            if ((k & prefmask) == prefix)
                atomicAdd(&hist[(k >> shift) & 0xFFu], 1);
        }
        __syncthreads();
        // wave 0: suffix-scan 256 bins (4 bins/lane), find threshold bin
        if (threadIdx.x < 64) {
            const int lane = threadIdx.x;
            const int h0 = hist[4 * lane + 0], h1 = hist[4 * lane + 1];
            const int h2 = hist[4 * lane + 2], h3 = hist[4 * lane + 3];
            const int local = h0 + h1 + h2 + h3;
            int x = local;                       // inclusive suffix sum over lanes
            for (int off = 1; off < 64; off <<= 1) {
                int y = __shfl_down(x, off, 64);
                if (lane + off < 64) x += y;
            }
            const int excl = x - local;          // keys in strictly higher lane-groups
            if (excl < remaining && remaining <= excl + local) {
                int acc = excl;
                const int hs[4] = { h3, h2, h1, h0 };       // descending bins
                const int bo[4] = { 3, 2, 1, 0 };
                for (int j = 0; j < 4; ++j) {
                    if (acc + hs[j] >= remaining) {
                        s_bin = 4 * lane + bo[j];
                        s_rem = remaining - acc;
                        break;
                    }
                    acc += hs[j];
                }
            }
        }
        __syncthreads();
        prefix  |= ((unsigned int)s_bin) << shift;
        prefmask |= (0xFFu << shift);
        remaining = s_rem;
        __syncthreads();   // everyone consumed s_bin/s_rem before next pass reuses them
    }

    const unsigned int thr = prefix;   // exact key of the boundary element
    for (int i = threadIdx.x; i < UU; i += 256) {
        unsigned int k = keys[i];
        if (k > thr) {
            int p = atomicAdd(&cnt_gt, 1);
            topk_idx[u * KK + p] = i;
            topk_val[u * KK + p] = key_to_float(k);
        } else if (k == thr) {
            int e = atomicAdd(&eq_cnt, 1);
            if (e < 64) eq_list[e] = i;
        }
    }
    __syncthreads();
    if (threadIdx.x == 0) {
        // fill slots [KK-remaining, KK) with smallest-index ties
        const int n = eq_cnt < 64 ? eq_cnt : 64;
        const float fv = key_to_float(thr);
        const int base = KK - remaining;
        for (int r = 0; r < remaining; ++r) {
            int mi = -1, mv = 0x7FFFFFFF;
            for (int j = 0; j < n; ++j) {
                int v = eq_list[j];
                if (v >= 0 && v < mv) { mv = v; mi = j; }
            }
            eq_list[mi] = -1;
            topk_idx[u * KK + base + r] = mv;
            topk_val[u * KK + base + r] = fv;
        }
    }
}

// ---------------------------------------------------------------------------
// Kernel 3: one 64-lane wave per batch element. Lanes 0..49 gather one
// neighbor each. All three loads (qos, avg, mask) are unconditional and
// independent -> single memory-latency round trip per wave.
// ---------------------------------------------------------------------------
__global__ __launch_bounds__(256) void gather_kernel(
    const float* __restrict__ qos, const void* __restrict__ mask,
    const float* __restrict__ avg, const int* __restrict__ time_ids,
    const int* __restrict__ user_ids, const int* __restrict__ service_ids,
    const int* __restrict__ topk_idx, const float* __restrict__ topk_val,
    const int* __restrict__ flag, float* __restrict__ out) {

    const int wave = (int)((blockIdx.x * blockDim.x + threadIdx.x) >> 6);
    const int lane = (int)(threadIdx.x & 63);
    if (wave >= BB) return;

    const int u = user_ids[wave];
    const int s = service_ids[wave];
    const int t = time_ids[wave];
    const float base = avg[(size_t)u * SS + s];
    const int fl = *flag;   // wave-uniform, L2-hot

    float wv = 0.0f, dv = 0.0f;
    if (lane < KK) {
        const int   idx = topk_idx[u * KK + lane];
        const float val = topk_val[u * KK + lane];
        const size_t off3 = ((size_t)idx * SS + s) * TT + t;
        const float q = qos[off3];                       // independent loads:
        const float a = avg[(size_t)idx * SS + s];       // all issue before use
        int m;
        if (fl == 0)       m = ((const int*)mask)[off3];
        else if (fl == 1)  m = (int)((const unsigned char*)mask)[off3];
        else               m = (((const float*)mask)[off3] != 0.0f) ? 1 : 0;
        wv = m ? val : 0.0f;
        dv = m ? val * (q - a) : 0.0f;
    }
    for (int m2 = 32; m2 >= 1; m2 >>= 1) {
        wv += __shfl_xor(wv, m2, 64);
        dv += __shfl_xor(dv, m2, 64);
    }
    if (lane == 0) {
        const float deviation = (wv > 0.0f) ? (dv / wv) : 0.0f;
        const float r = base + deviation;
        out[wave] = (r > 0.0f) ? r : 0.0f;
    }
}

extern "C" void kernel_launch(void* const* d_in, const int* in_sizes, int n_in,
                              void* d_out, int out_size, void* d_ws, size_t ws_size,
                              hipStream_t stream) {
    const float* qos      = (const float*)d_in[0];
    const void*  mask     = d_in[1];
    const float* avg      = (const float*)d_in[2];
    const float* user_sim = (const float*)d_in[3];
    const int* time_ids    = (const int*)d_in[4];
    const int* user_ids    = (const int*)d_in[5];
    const int* service_ids = (const int*)d_in[6];
    float* out = (float*)d_out;

    int*   topk_idx = (int*)d_ws;
    float* topk_val = (float*)((char*)d_ws + (size_t)UU * KK * 4);
    int*   flag     = (int*)((char*)d_ws + (size_t)UU * KK * 8);

    detect_mask<<<1, 256, 0, stream>>>((const unsigned int*)mask, flag);
    topk_select<<<UU, 256, 0, stream>>>(user_sim, topk_idx, topk_val);
    gather_kernel<<<(BB * 64) / 256, 256, 0, stream>>>(
        qos, mask, avg, time_ids, user_ids, service_ids,
        topk_idx, topk_val, flag, out);
}

// Round 3
// 927.765 us; speedup vs baseline: 1.1419x; 1.0217x over previous
//
#include <hip/hip_runtime.h>

#define UU 3000
#define SS 1500
#define TT 32
#define BB 16384
#define KK 50
#define RPT 12   // ceil(3000/256) register keys per thread

// order-preserving float<->uint map
__device__ __forceinline__ unsigned int float_to_key(float f) {
    unsigned int b = __float_as_uint(f);
    return (b & 0x80000000u) ? ~b : (b | 0x80000000u);
}
__device__ __forceinline__ float key_to_float(unsigned int k) {
    return (k & 0x80000000u) ? __uint_as_float(k & 0x7FFFFFFFu)
                             : __uint_as_float(~k);
}

// ---------------------------------------------------------------------------
// Kernel 1: per-user top-50 via 4-pass 8-bit radix select, keys in REGISTERS.
// Block u < UU: top-50 of user_sim row u -> interleaved (idx, val_bits) pairs.
// Block u == UU: classify mask buffer encoding into *flag
//   (0 = int32 words 0/1, 1 = uint8 bytes, 2 = float32 0.0/1.0).
// Padding keys (i >= UU) are 0 -> bin 0; every real key has top byte >= 0x40
// (values >= -1.0), so padding can never reach the selection threshold.
// ---------------------------------------------------------------------------
__global__ __launch_bounds__(256) void topk_select(const float* __restrict__ user_sim,
                                                   int2* __restrict__ topk,
                                                   const unsigned int* __restrict__ mask,
                                                   int* __restrict__ flag) {
    const int u = blockIdx.x;

    if (u == UU) {   // ---- mask-encoding probe ----
        __shared__ int bad_i32, bad_f32;
        if (threadIdx.x == 0) { bad_i32 = 0; bad_f32 = 0; }
        __syncthreads();
        for (int i = threadIdx.x; i < 4096; i += 256) {
            unsigned int w = mask[i];
            if (w > 1u) bad_i32 = 1;
            if (w != 0u && w != 0x3F800000u) bad_f32 = 1;
        }
        __syncthreads();
        if (threadIdx.x == 0) {
            int f = 0;
            if (bad_i32) f = bad_f32 ? 1 : 2;
            *flag = f;
        }
        return;
    }

    __shared__ int hist[256];
    __shared__ int s_bin, s_rem;
    __shared__ int cnt_gt, eq_cnt;
    __shared__ int eq_list[64];

    const float* row = user_sim + (size_t)u * UU;

    unsigned int keys[RPT];
    #pragma unroll
    for (int j = 0; j < RPT; ++j) {
        const int i = threadIdx.x + 256 * j;
        keys[j] = (i < UU) ? float_to_key(row[i]) : 0u;
    }
    if (threadIdx.x == 0) { cnt_gt = 0; eq_cnt = 0; }

    unsigned int prefix = 0u, prefmask = 0u;
    int remaining = KK;

    for (int pass = 0; pass < 4; ++pass) {
        const int shift = 24 - pass * 8;
        hist[threadIdx.x] = 0;
        __syncthreads();
        #pragma unroll
        for (int j = 0; j < RPT; ++j) {
            const unsigned int k = keys[j];
            if ((k & prefmask) == prefix)
                atomicAdd(&hist[(k >> shift) & 0xFFu], 1);
        }
        __syncthreads();
        // wave 0: suffix-scan 256 bins (4 bins/lane), find threshold bin
        if (threadIdx.x < 64) {
            const int lane = threadIdx.x;
            const int h0 = hist[4 * lane + 0], h1 = hist[4 * lane + 1];
            const int h2 = hist[4 * lane + 2], h3 = hist[4 * lane + 3];
            const int local = h0 + h1 + h2 + h3;
            int x = local;                       // inclusive suffix sum over lanes
            for (int off = 1; off < 64; off <<= 1) {
                int y = __shfl_down(x, off, 64);
                if (lane + off < 64) x += y;
            }
            const int excl = x - local;          // keys in strictly higher lane-groups
            if (excl < remaining && remaining <= excl + local) {
                int acc = excl;
                const int hs[4] = { h3, h2, h1, h0 };   // descending bins
                const int bo[4] = { 3, 2, 1, 0 };
                for (int jj = 0; jj < 4; ++jj) {
                    if (acc + hs[jj] >= remaining) {
                        s_bin = 4 * lane + bo[jj];
                        s_rem = remaining - acc;
                        break;
                    }
                    acc += hs[jj];
                }
            }
        }
        __syncthreads();
        prefix  |= ((unsigned int)s_bin) << shift;
        prefmask |= (0xFFu << shift);
        remaining = s_rem;
        __syncthreads();   // all threads consumed s_bin/s_rem before reuse
    }

    const unsigned int thr = prefix;   // exact key of the boundary element
    #pragma unroll
    for (int j = 0; j < RPT; ++j) {
        const unsigned int k = keys[j];
        const int i = threadIdx.x + 256 * j;
        if (k > thr) {
            int p = atomicAdd(&cnt_gt, 1);
            topk[u * KK + p] = make_int2(i, __float_as_int(key_to_float(k)));
        } else if (k == thr) {
            int e = atomicAdd(&eq_cnt, 1);
            if (e < 64) eq_list[e] = i;
        }
    }
    __syncthreads();
    if (threadIdx.x == 0) {
        // fill slots [KK-remaining, KK) with smallest-index ties (jax tie-break)
        const int n = eq_cnt < 64 ? eq_cnt : 64;
        const int vb = __float_as_int(key_to_float(thr));
        const int base = KK - remaining;
        for (int r = 0; r < remaining; ++r) {
            int mi = -1, mv = 0x7FFFFFFF;
            for (int jj = 0; jj < n; ++jj) {
                int v = eq_list[jj];
                if (v >= 0 && v < mv) { mv = v; mi = jj; }
            }
            eq_list[mi] = -1;
            topk[u * KK + base + r] = make_int2(mv, vb);
        }
    }
}

// ---------------------------------------------------------------------------
// Kernel 2: one 64-lane wave per batch element. Lanes 0..49 gather one
// neighbor each (pair load + 3 independent scattered loads), butterfly-
// reduce sim_sum / dev_sum across the wave.
// ---------------------------------------------------------------------------
__global__ __launch_bounds__(256) void gather_kernel(
    const float* __restrict__ qos, const void* __restrict__ mask,
    const float* __restrict__ avg, const int* __restrict__ time_ids,
    const int* __restrict__ user_ids, const int* __restrict__ service_ids,
    const int2* __restrict__ topk, const int* __restrict__ flag,
    float* __restrict__ out) {

    const int wave = (int)((blockIdx.x * blockDim.x + threadIdx.x) >> 6);
    const int lane = (int)(threadIdx.x & 63);
    if (wave >= BB) return;

    const int u = user_ids[wave];
    const int s = service_ids[wave];
    const int t = time_ids[wave];
    const float base = avg[(size_t)u * SS + s];
    const int fl = *flag;   // wave-uniform, L2-hot

    float wv = 0.0f, dv = 0.0f;
    if (lane < KK) {
        const int2  tv  = topk[u * KK + lane];
        const int   idx = tv.x;
        const float val = __int_as_float(tv.y);
        const size_t off3 = ((size_t)idx * SS + s) * TT + t;
        const float q = qos[off3];                     // independent loads —
        const float a = avg[(size_t)idx * SS + s];     // all issue before use
        int m;
        if (fl == 0)       m = ((const int*)mask)[off3];
        else if (fl == 1)  m = (int)((const unsigned char*)mask)[off3];
        else               m = (((const float*)mask)[off3] != 0.0f) ? 1 : 0;
        wv = m ? val : 0.0f;
        dv = m ? val * (q - a) : 0.0f;
    }
    for (int m2 = 32; m2 >= 1; m2 >>= 1) {
        wv += __shfl_xor(wv, m2, 64);
        dv += __shfl_xor(dv, m2, 64);
    }
    if (lane == 0) {
        const float deviation = (wv > 0.0f) ? (dv / wv) : 0.0f;
        const float r = base + deviation;
        out[wave] = (r > 0.0f) ? r : 0.0f;
    }
}

extern "C" void kernel_launch(void* const* d_in, const int* in_sizes, int n_in,
                              void* d_out, int out_size, void* d_ws, size_t ws_size,
                              hipStream_t stream) {
    const float* qos      = (const float*)d_in[0];
    const void*  mask     = d_in[1];
    const float* avg      = (const float*)d_in[2];
    const float* user_sim = (const float*)d_in[3];
    const int* time_ids    = (const int*)d_in[4];
    const int* user_ids    = (const int*)d_in[5];
    const int* service_ids = (const int*)d_in[6];
    float* out = (float*)d_out;

    // ws layout: [topk pairs: U*K int2][flag: int]
    int2* topk = (int2*)d_ws;
    int*  flag = (int*)((char*)d_ws + (size_t)UU * KK * 8);

    topk_select<<<UU + 1, 256, 0, stream>>>(user_sim, topk,
                                            (const unsigned int*)mask, flag);
    gather_kernel<<<(BB * 64) / 256, 256, 0, stream>>>(
        qos, mask, avg, time_ids, user_ids, service_ids, topk, flag, out);
}